// Round 1
// baseline (352.860 us; speedup 1.0000x reference)
//
#include <hip/hip_runtime.h>

#define THRESH 0.95f
#define MAXL 64

// Kernel A: exact sequential integrate-and-fire scan, one thread per batch.
// Replicates the reference f32 arithmetic exactly:
//   dc = 1 - integ; integ += a; fire = integ > 0.95; if fire: integ -= 1
// Records first MAXL fires: time index, cur (=dc) and remainds (=a - dc).
__global__ void cif_scan(const float* __restrict__ alphas, int T, int B,
                         int* __restrict__ nf, int* __restrict__ fireT,
                         float* __restrict__ curAt, float* __restrict__ remAt) {
    int b = blockIdx.x * blockDim.x + threadIdx.x;
    if (b >= B) return;
    const float* arow = alphas + (size_t)b * T;
    float integ = 0.0f;
    int n = 0;
    for (int t = 0; t < T; ++t) {
        float a = arow[t];
        float dc = 1.0f - integ;   // dist_completion (pre-add)
        integ = integ + a;
        if (integ > THRESH) {
            if (n < MAXL) {
                fireT[b * MAXL + n] = t;
                curAt[b * MAXL + n] = dc;
                remAt[b * MAXL + n] = a - dc;
            }
            ++n;
            integ = integ - 1.0f;
        }
    }
    nf[b] = (n < MAXL) ? n : MAXL;
}

// Kernel B: one block per (batch, label). Each output row out[b,k,:] is a
// weighted sum over a contiguous t-segment:
//   rem[k-1]*h[t_prev]  +  sum_{t in (t_prev, t_f)} a_t*h[t]  +  cur[k]*h[t_f]
// accumulated in ascending t (same order as the reference scan).
// Labels k >= fire count write zeros (d_out is poisoned by the harness).
__global__ __launch_bounds__(512) void cif_gather(
    const float* __restrict__ hidden, const float* __restrict__ alphas,
    int T, int H,
    const int* __restrict__ nf, const int* __restrict__ fireT,
    const float* __restrict__ curAt, const float* __restrict__ remAt,
    float* __restrict__ out) {
    int b = blockIdx.x / MAXL;
    int k = blockIdx.x % MAXL;

    int valid = (k < nf[b]);
    int tf = 0, t0 = 0, tp = 0;
    float rw = 0.0f, cw = 0.0f;
    if (valid) {
        tf = fireT[b * MAXL + k];
        cw = curAt[b * MAXL + k];
        if (k > 0) {
            tp = fireT[b * MAXL + k - 1];
            rw = remAt[b * MAXL + k - 1];
            t0 = tp + 1;
        }
    }

    const float* hb   = hidden + (size_t)b * T * H;
    const float* arow = alphas + (size_t)b * T;
    size_t obase = (size_t)blockIdx.x * H;

    for (int h = threadIdx.x; h < H; h += blockDim.x) {
        float acc = 0.0f;
        if (valid) {
            if (k > 0) acc = rw * hb[(size_t)tp * H + h];
            for (int t = t0; t < tf; ++t)
                acc += arow[t] * hb[(size_t)t * H + h];
            acc += cw * hb[(size_t)tf * H + h];
        }
        out[obase + h] = acc;
    }
}

extern "C" void kernel_launch(void* const* d_in, const int* in_sizes, int n_in,
                              void* d_out, int out_size, void* d_ws, size_t ws_size,
                              hipStream_t stream) {
    const float* hidden = (const float*)d_in[0];
    const float* alphas = (const float*)d_in[1];
    float* out = (float*)d_out;

    long BT  = in_sizes[1];          // B*T
    long BTH = in_sizes[0];          // B*T*H
    int H = (int)(BTH / BT);         // 512
    int B = (int)((long)out_size / ((long)MAXL * H)); // 32
    int T = (int)(BT / B);           // 2000

    char* ws = (char*)d_ws;
    int*   nf    = (int*)ws;                              // B ints
    int*   fireT = (int*)(ws + 256);                      // B*MAXL ints
    float* curAt = (float*)(ws + 256 + (size_t)B * MAXL * 4);
    float* remAt = (float*)(ws + 256 + 2 * (size_t)B * MAXL * 4);

    int sb = 64;
    cif_scan<<<(B + sb - 1) / sb, sb, 0, stream>>>(alphas, T, B, nf, fireT, curAt, remAt);
    cif_gather<<<B * MAXL, 512, 0, stream>>>(hidden, alphas, T, H, nf, fireT, curAt, remAt, out);
}

// Round 2
// 83.208 us; speedup vs baseline: 4.2407x; 4.2407x over previous
//
#include <hip/hip_runtime.h>

#define THRESH 0.95f
#define MAXL 64

// Kernel A v2: one block per batch. 64 threads stage alphas[b,:] into LDS
// (coalesced float4), then thread 0 runs the bit-exact serial
// integrate-and-fire recurrence reading LDS in 16-float register groups with
// double-buffered prefetch (4x ds_read_b128 in flight while the previous
// group's dependent VALU chain runs).
__global__ __launch_bounds__(64) void cif_scan(
    const float* __restrict__ alphas, int T, int B,
    int* __restrict__ nf, int* __restrict__ fireT,
    float* __restrict__ curAt, float* __restrict__ remAt) {
    __shared__ __align__(16) float sa[2048];
    int b = blockIdx.x;
    const float* arow = alphas + (size_t)b * T;

    // cooperative stage: vectorized when layout permits
    int tid = threadIdx.x;
    int T4 = T >> 2;
    if ((((uintptr_t)arow) & 15) == 0) {
        const float4* g4 = (const float4*)arow;
        float4* s4 = (float4*)sa;
        for (int i = tid; i < T4; i += 64) s4[i] = g4[i];
        for (int i = T4 * 4 + tid; i < T; i += 64) sa[i] = arow[i];
    } else {
        for (int i = tid; i < T; i += 64) sa[i] = arow[i];
    }
    __syncthreads();

    if (tid != 0) return;

    float integ = 0.0f;
    int n = 0;
    const float4* s4 = (const float4*)sa;
    int ngroups = T / 16;          // 16-float groups

    float4 cbuf0, cbuf1, cbuf2, cbuf3;
    float4 nbuf0, nbuf1, nbuf2, nbuf3;
    if (ngroups > 0) {
        cbuf0 = s4[0]; cbuf1 = s4[1]; cbuf2 = s4[2]; cbuf3 = s4[3];
    }
    for (int g = 0; g < ngroups; ++g) {
        if (g + 1 < ngroups) {
            int base = (g + 1) * 4;
            nbuf0 = s4[base]; nbuf1 = s4[base + 1];
            nbuf2 = s4[base + 2]; nbuf3 = s4[base + 3];
        }
        float v[16];
        v[0] = cbuf0.x; v[1] = cbuf0.y; v[2]  = cbuf0.z; v[3]  = cbuf0.w;
        v[4] = cbuf1.x; v[5] = cbuf1.y; v[6]  = cbuf1.z; v[7]  = cbuf1.w;
        v[8] = cbuf2.x; v[9] = cbuf2.y; v[10] = cbuf2.z; v[11] = cbuf2.w;
        v[12] = cbuf3.x; v[13] = cbuf3.y; v[14] = cbuf3.z; v[15] = cbuf3.w;
        int tbase = g * 16;
        #pragma unroll
        for (int i = 0; i < 16; ++i) {
            float a = v[i];
            float pre = integ;           // integ before add (for dist_completion)
            integ = integ + a;           // exact reference rounding order
            if (integ > THRESH) {        // fire (rare branch)
                if (n < MAXL) {
                    float dc = 1.0f - pre;
                    fireT[b * MAXL + n] = tbase + i;
                    curAt[b * MAXL + n] = dc;
                    remAt[b * MAXL + n] = a - dc;
                }
                ++n;
                integ = integ - 1.0f;    // exact (Sterbenz)
            }
        }
        cbuf0 = nbuf0; cbuf1 = nbuf1; cbuf2 = nbuf2; cbuf3 = nbuf3;
    }
    // scalar tail (T % 16)
    for (int t = ngroups * 16; t < T; ++t) {
        float a = sa[t];
        float pre = integ;
        integ = integ + a;
        if (integ > THRESH) {
            if (n < MAXL) {
                float dc = 1.0f - pre;
                fireT[b * MAXL + n] = t;
                curAt[b * MAXL + n] = dc;
                remAt[b * MAXL + n] = a - dc;
            }
            ++n;
            integ = integ - 1.0f;
        }
    }
    nf[b] = (n < MAXL) ? n : MAXL;
}

// Kernel B: one block per (batch, label). out[b,k,:] is a weighted sum over a
// contiguous t-segment, accumulated in ascending t (reference scan order):
//   rem[k-1]*h[t_prev] + sum_{t in (t_prev, t_f)} a_t*h[t] + cur[k]*h[t_f]
// Labels k >= fire count write zeros (d_out is poisoned by the harness).
__global__ __launch_bounds__(512) void cif_gather(
    const float* __restrict__ hidden, const float* __restrict__ alphas,
    int T, int H,
    const int* __restrict__ nf, const int* __restrict__ fireT,
    const float* __restrict__ curAt, const float* __restrict__ remAt,
    float* __restrict__ out) {
    int b = blockIdx.x / MAXL;
    int k = blockIdx.x % MAXL;

    int valid = (k < nf[b]);
    int tf = 0, t0 = 0, tp = 0;
    float rw = 0.0f, cw = 0.0f;
    if (valid) {
        tf = fireT[b * MAXL + k];
        cw = curAt[b * MAXL + k];
        if (k > 0) {
            tp = fireT[b * MAXL + k - 1];
            rw = remAt[b * MAXL + k - 1];
            t0 = tp + 1;
        }
    }

    const float* hb   = hidden + (size_t)b * T * H;
    const float* arow = alphas + (size_t)b * T;
    size_t obase = (size_t)blockIdx.x * H;

    for (int h = threadIdx.x; h < H; h += blockDim.x) {
        float acc = 0.0f;
        if (valid) {
            if (k > 0) acc = rw * hb[(size_t)tp * H + h];
            for (int t = t0; t < tf; ++t)
                acc += arow[t] * hb[(size_t)t * H + h];
            acc += cw * hb[(size_t)tf * H + h];
        }
        out[obase + h] = acc;
    }
}

extern "C" void kernel_launch(void* const* d_in, const int* in_sizes, int n_in,
                              void* d_out, int out_size, void* d_ws, size_t ws_size,
                              hipStream_t stream) {
    const float* hidden = (const float*)d_in[0];
    const float* alphas = (const float*)d_in[1];
    float* out = (float*)d_out;

    long BT  = in_sizes[1];          // B*T
    long BTH = in_sizes[0];          // B*T*H
    int H = (int)(BTH / BT);         // 512
    int B = (int)((long)out_size / ((long)MAXL * H)); // 32
    int T = (int)(BT / B);           // 2000

    char* ws = (char*)d_ws;
    int*   nf    = (int*)ws;                              // B ints
    int*   fireT = (int*)(ws + 256);                      // B*MAXL ints
    float* curAt = (float*)(ws + 256 + (size_t)B * MAXL * 4);
    float* remAt = (float*)(ws + 256 + 2 * (size_t)B * MAXL * 4);

    cif_scan<<<B, 64, 0, stream>>>(alphas, T, B, nf, fireT, curAt, remAt);
    cif_gather<<<B * MAXL, 512, 0, stream>>>(hidden, alphas, T, H, nf, fireT, curAt, remAt, out);
}